// Round 14
// baseline (210.830 us; speedup 1.0000x reference)
//
#include <hip/hip_runtime.h>
#include <hip/hip_bf16.h>

// Problem constants
#define NB    2048   // batch
#define SS    200    // seq len
#define NTIL  13     // s-tiles of 16 (208 padded)
#define DSEQ  256
#define DITEM 64
#define AA    128    // attn dim (H=1, HD=128)

typedef __bf16 bf16x8 __attribute__((ext_vector_type(8)));
typedef float  f32x4  __attribute__((ext_vector_type(4)));

__device__ __forceinline__ float prelu_f(float x, float a) { return x >= 0.f ? x : a * x; }

// 16-lane reduce via DPP row_ror — VALU pipe only; result valid in all 16 lanes.
#define ROR_F(x, n) __int_as_float(__builtin_amdgcn_update_dpp(0, __float_as_int(x), 0x120 + (n), 0xf, 0xf, true))
__device__ __forceinline__ float row_sum16(float x) {
    x += ROR_F(x, 1); x += ROR_F(x, 2); x += ROR_F(x, 4); x += ROR_F(x, 8);
    return x;
}
__device__ __forceinline__ float row_max16(float x) {
    x = fmaxf(x, ROR_F(x, 1)); x = fmaxf(x, ROR_F(x, 2));
    x = fmaxf(x, ROR_F(x, 4)); x = fmaxf(x, ROR_F(x, 8));
    return x;
}

// ---------------- prep: W_k|W_v -> bf16 [256 rows][512B], XOR-swizzled within rows
__global__ void prep_kernel(const float* __restrict__ Wk, const float* __restrict__ Wv,
                            __hip_bfloat16* __restrict__ Wb) {
    int idx = blockIdx.x * 256 + threadIdx.x;   // 256 blocks -> 65536
    int a = idx >> 8, d = idx & 255;
    float v = (a < 128) ? Wk[a * 256 + d] : Wv[(a - 128) * 256 + d];
    int boff = (d * 2) ^ ((a & 7) << 4);
    Wb[a * 256 + (boff >> 1)] = __float2bfloat16(v);
}

// per-thread staging: thread handles row srow, 64B chunk `chunk` (4 f32x4)
#define ISSUE(tt)                                                               \
    {                                                                           \
        int r_ = (tt) * 16 + srow; r_ = r_ < SS ? r_ : SS - 1;                  \
        const float* xp_ = X + ((size_t)b * SS + r_) * DSEQ + chunk * 16;       \
        s0 = *reinterpret_cast<const f32x4*>(xp_);                              \
        s1 = *reinterpret_cast<const f32x4*>(xp_ + 4);                          \
        s2 = *reinterpret_cast<const f32x4*>(xp_ + 8);                          \
        s3 = *reinterpret_cast<const f32x4*>(xp_ + 12);                         \
    }

#define STAGE(buf)                                                              \
    {                                                                           \
        bf16x8 va_, vb_;                                                        \
        va_[0] = (__bf16)s0[0]; va_[1] = (__bf16)s0[1];                         \
        va_[2] = (__bf16)s0[2]; va_[3] = (__bf16)s0[3];                         \
        va_[4] = (__bf16)s1[0]; va_[5] = (__bf16)s1[1];                         \
        va_[6] = (__bf16)s1[2]; va_[7] = (__bf16)s1[3];                         \
        vb_[0] = (__bf16)s2[0]; vb_[1] = (__bf16)s2[1];                         \
        vb_[2] = (__bf16)s2[2]; vb_[3] = (__bf16)s2[3];                         \
        vb_[4] = (__bf16)s3[0]; vb_[5] = (__bf16)s3[1];                         \
        vb_[6] = (__bf16)s3[2]; vb_[7] = (__bf16)s3[3];                         \
        *reinterpret_cast<bf16x8*>(xbase + (buf) * 8192 + wr0) = va_;           \
        *reinterpret_cast<bf16x8*>(xbase + (buf) * 8192 + wr1) = vb_;           \
    }

// deferred online-softmax + V-fold of tile `tp` (scores of tp are in sp[tp&1])
#define SMFOLD(tp)                                                              \
    {                                                                           \
        const int q_ = (tp) & 1;                                                \
        const int s0_ = (tp) * 16;                                              \
        f32x4 r_ = *reinterpret_cast<const f32x4*>(&sp[q_][c][0]);              \
        float sc_ = (r_[0] + r_[1] + r_[2] + r_[3]) * inv_scale;                \
        sc_ = mask_lds[s0_ + c] ? -1e9f : sc_;                                  \
        if (tid < 16) score_buf[s0_ + tid] = sc_;                               \
        float tmax_ = row_max16(sc_);                                           \
        float nm_ = fmaxf(m, tmax_);                                            \
        float fs_ = __expf(m - nm_);                                            \
        float e_  = __expf(sc_ - nm_);                                          \
        float ls_ = row_sum16(e_);                                              \
        l = l * fs_ + ls_; m = nm_;                                             \
        oacc0 *= fs_; oacc1 *= fs_;                                             \
        _Pragma("unroll")                                                       \
        for (int i_ = 0; i_ < 4; i_++) {                                        \
            float ew_ = __shfl(e_, (lane & 48) | (rg * 4 + i_), 64);            \
            oacc0 += ew_ * prelu_f(aVp0[i_], pa);                               \
            oacc1 += ew_ * prelu_f(aVp1[i_], pa);                               \
        }                                                                       \
    }

// ---------------- main: 256-thread block (4 waves) per batch row.
// Wave w owns K-cols [32w,32w+32) (VGPR-resident) and V-cols [32w,32w+32)
// (streamed from L2). Small blocks -> 3-4 independent convoys per CU.
__global__ __launch_bounds__(256)
void pool_main(
    const float* __restrict__ X,      // [2048,200,256]
    const int*   __restrict__ maskp,  // [2048,200] 1 = pad
    const float* __restrict__ temb,   // [2048,64]
    const float* __restrict__ Wq,     // [128,64]
    const float* __restrict__ Wker,   // [128,128]
    const float* __restrict__ ffnW,   // [256,128]
    const float* __restrict__ ffnb,   // [256]
    const float* __restrict__ prelu_a,
    const __hip_bfloat16* __restrict__ Wb,  // ws: swizzled bf16 weights [256][256]
    float* __restrict__ out)          // [2048*256] ffn, then [2048*200] attn
{
    __shared__ __hip_bfloat16 Xt[2][16][256];    // 16 KB, dbuf bf16 X tile (swizzled)
    __shared__ float sp[2][16][4];               // [par][s][wave] score partials
    __shared__ float score_buf[208];
    __shared__ float out_vec[AA];
    __shared__ float tq[DITEM];
    __shared__ float Qv[AA];
    __shared__ float uv[AA];
    __shared__ int   mask_lds[208];

    const int tid  = threadIdx.x;     // 0..255
    const int w    = tid >> 6;        // wave 0..3
    const int lane = tid & 63;
    const int c    = lane & 15;       // D col (a-col within 16-group) / staging
    const int rg   = lane >> 4;       // D row group (s = rg*4+i)
    const int b    = blockIdx.x;
    const float pa = *prelu_a;
    const float inv_scale = 0.08838834764831845f;  // 1/sqrt(128)

    const int srow  = tid >> 4;       // staging row 0..15
    const int chunk = tid & 15;       // 64B chunk in row
    const int wswz  = (srow & 7) << 4;
    const int wr0   = srow * 512 + ((chunk * 32) ^ wswz);
    const int wr1   = srow * 512 + ((chunk * 32 + 16) ^ wswz);
    char* xbase = (char*)&Xt[0][0][0];
    const int rswz = (c & 7) << 4;

    // ---- K weight fragments (2 col-groups) -> VGPRs; V stays in L2
    bf16x8 wk0[8], wk1[8];
    const char* kb0 = (const char*)Wb + (size_t)(32 * w + c) * 512;
    const char* kb1 = kb0 + 16 * 512;
    const char* vb0 = (const char*)Wb + 65536 + (size_t)(32 * w + c) * 512;
    const char* vb1 = vb0 + 16 * 512;
    #pragma unroll
    for (int k = 0; k < 8; k++) {
        const int o = (k * 64 + rg * 16) ^ rswz;
        wk0[k] = *reinterpret_cast<const bf16x8*>(kb0 + o);
        wk1[k] = *reinterpret_cast<const bf16x8*>(kb1 + o);
    }

    // ---- small staging + X tile-0 issue
    if (tid < DITEM) tq[tid] = temb[(size_t)b * DITEM + tid];
    if (tid < 208)   mask_lds[tid] = (tid < SS) ? maskp[(size_t)b * SS + tid] : 1;
    f32x4 s0, s1, s2, s3;
    ISSUE(0);
    __syncthreads();

    // ---- Q = prelu(W_q @ t)
    if (tid < AA) {
        float acc = 0.f;
        #pragma unroll
        for (int d4 = 0; d4 < 16; d4++) {
            f32x4 tv = *reinterpret_cast<const f32x4*>(&tq[d4 * 4]);
            f32x4 wq4 = *reinterpret_cast<const f32x4*>(Wq + (size_t)tid * DITEM + d4 * 4);
            acc += wq4[0]*tv[0] + wq4[1]*tv[1] + wq4[2]*tv[2] + wq4[3]*tv[3];
        }
        Qv[tid] = prelu_f(acc, pa);
    }
    __syncthreads();

    // ---- u = W_kernel @ Q
    if (tid < AA) {
        float acc = 0.f;
        #pragma unroll
        for (int d4 = 0; d4 < 32; d4++) {
            f32x4 qv = *reinterpret_cast<const f32x4*>(&Qv[d4 * 4]);
            f32x4 wv4 = *reinterpret_cast<const f32x4*>(Wker + (size_t)tid * AA + d4 * 4);
            acc += wv4[0]*qv[0] + wv4[1]*qv[1] + wv4[2]*qv[2] + wv4[3]*qv[3];
        }
        uv[tid] = acc;
    }
    __syncthreads();
    const float uw0 = uv[32 * w + c];
    const float uw1 = uv[32 * w + 16 + c];

    // tile 0 -> LDS
    STAGE(0);
    __syncthreads();

    // ---- main loop: 1 barrier per tile, deferred softmax, 4 MFMA chains/tile
    float m = -INFINITY, l = 0.f, oacc0 = 0.f, oacc1 = 0.f;
    f32x4 aVp0 = {0.f,0.f,0.f,0.f}, aVp1 = {0.f,0.f,0.f,0.f};

    for (int t = 0; t < NTIL; t++) {
        if (t + 1 < NTIL) ISSUE(t + 1);

        const char* rb = xbase + (t & 1) * 8192 + c * 512;

        if (t > 0) SMFOLD(t - 1);

        f32x4 aK0 = {0.f,0.f,0.f,0.f}, aK1 = {0.f,0.f,0.f,0.f};
        f32x4 aV0 = {0.f,0.f,0.f,0.f}, aV1 = {0.f,0.f,0.f,0.f};
        #pragma unroll
        for (int k = 0; k < 8; k++) {
            const int o = (k * 64 + rg * 16) ^ rswz;
            bf16x8 af  = *reinterpret_cast<const bf16x8*>(rb + o);
            bf16x8 bv0 = *reinterpret_cast<const bf16x8*>(vb0 + o);  // L2 hit
            bf16x8 bv1 = *reinterpret_cast<const bf16x8*>(vb1 + o);  // L2 hit
            aK0 = __builtin_amdgcn_mfma_f32_16x16x32_bf16(af, wk0[k], aK0, 0, 0, 0);
            aK1 = __builtin_amdgcn_mfma_f32_16x16x32_bf16(af, wk1[k], aK1, 0, 0, 0);
            aV0 = __builtin_amdgcn_mfma_f32_16x16x32_bf16(af, bv0,   aV0, 0, 0, 0);
            aV1 = __builtin_amdgcn_mfma_f32_16x16x32_bf16(af, bv1,   aV1, 0, 0, 0);
        }
        float pr[4];
        #pragma unroll
        for (int i = 0; i < 4; i++)
            pr[i] = row_sum16(prelu_f(aK0[i], pa) * uw0 + prelu_f(aK1[i], pa) * uw1);
        if (c == 0) {
            #pragma unroll
            for (int i = 0; i < 4; i++) sp[t & 1][rg * 4 + i][w] = pr[i];
        }
        aVp0 = aV0; aVp1 = aV1;

        if (t + 1 < NTIL) STAGE((t + 1) & 1);
        __syncthreads();
    }

    // ---- epilogue: fold last tile, reduce, outputs
    SMFOLD(NTIL - 1);
    oacc0 += __shfl_xor(oacc0, 16, 64); oacc0 += __shfl_xor(oacc0, 32, 64);
    oacc1 += __shfl_xor(oacc1, 16, 64); oacc1 += __shfl_xor(oacc1, 32, 64);
    const float invl = 1.0f / l;
    if (lane < 16) {
        out_vec[32 * w + lane]      = oacc0 * invl;
        out_vec[32 * w + 16 + lane] = oacc1 * invl;
    }
    __syncthreads();

    // attn output [b][200]
    if (tid < SS)
        out[(size_t)NB * DSEQ + (size_t)b * SS + tid] = __expf(score_buf[tid] - m) * invl;

    // FFN: out[o] = prelu(b[o] + sum_a ov[a]*ffnW[o][a]), o = tid
    {
        float acc = ffnb[tid];
        #pragma unroll 8
        for (int a4 = 0; a4 < 32; a4++) {
            f32x4 ov = *reinterpret_cast<const f32x4*>(&out_vec[a4 * 4]);
            f32x4 wv4 = *reinterpret_cast<const f32x4*>(ffnW + (size_t)tid * AA + a4 * 4);
            acc += wv4[0]*ov[0] + wv4[1]*ov[1] + wv4[2]*ov[2] + wv4[3]*ov[3];
        }
        out[(size_t)b * DSEQ + tid] = prelu_f(acc, pa);
    }
}

extern "C" void kernel_launch(void* const* d_in, const int* in_sizes, int n_in,
                              void* d_out, int out_size, void* d_ws, size_t ws_size,
                              hipStream_t stream) {
    const float* X    = (const float*)d_in[0];
    const int*   mask = (const int*)  d_in[1];
    const float* temb = (const float*)d_in[2];
    const float* Wq   = (const float*)d_in[3];
    const float* Wk   = (const float*)d_in[4];
    const float* Wv   = (const float*)d_in[5];
    const float* Wker = (const float*)d_in[6];
    const float* ffnW = (const float*)d_in[7];
    const float* ffnb = (const float*)d_in[8];
    const float* pa   = (const float*)d_in[9];
    float* out = (float*)d_out;

    __hip_bfloat16* Wb = (__hip_bfloat16*)d_ws;

    prep_kernel<<<256, 256, 0, stream>>>(Wk, Wv, Wb);
    pool_main<<<NB, 256, 0, stream>>>(X, mask, temb, Wq, Wker, ffnW, ffnb, pa, Wb, out);
}